// Round 13
// baseline (380.388 us; speedup 1.0000x reference)
//
#include <hip/hip_runtime.h>
#include <hip/hip_fp16.h>
#include <math.h>

#define SEQ    4096
#define DMODEL 1024

typedef _Float16 half8   __attribute__((ext_vector_type(8)));
typedef _Float16 half4v  __attribute__((ext_vector_type(4)));
typedef float    floatx4 __attribute__((ext_vector_type(4)));
typedef float    floatx16 __attribute__((ext_vector_type(16)));

__device__ inline void split_val(float v, _Float16& h, _Float16& l) {
    _Float16 hh = (_Float16)v;
    h = hh;
    l = (_Float16)(v - (float)hh);
}

// ---------------------------------------------------------------------------
// Fused prep: blocks 0..3071 transpose wq/wk/wv (32x32 tiles); blocks
// 3072..4095 split x into hi/lo fp16 (4 float4 per thread = full x).
// ---------------------------------------------------------------------------
__global__ __launch_bounds__(256) void prep(const float* __restrict__ x,
                                            const float* __restrict__ wq,
                                            const float* __restrict__ wk,
                                            const float* __restrict__ wv,
                                            _Float16* __restrict__ x_hi,
                                            _Float16* __restrict__ x_lo,
                                            _Float16* __restrict__ wqkT_hi,
                                            _Float16* __restrict__ wqkT_lo,
                                            _Float16* __restrict__ wvT) {
    __shared__ float tile[32][33];
    const int b = blockIdx.x;
    if (b < 3072) {
        const int which = b >> 10;           // 0=wq 1=wk 2=wv
        const int bb = b & 1023;
        const int c0 = (bb & 31) * 32;
        const int r0 = (bb >> 5) * 32;
        const float* w = (which == 0) ? wq : (which == 1) ? wk : wv;
        const int tx = threadIdx.x & 31, ty = threadIdx.x >> 5;
#pragma unroll
        for (int j = 0; j < 4; ++j)
            tile[ty * 4 + j][tx] = w[(size_t)(r0 + ty * 4 + j) * DMODEL + c0 + tx];
        __syncthreads();
        if (which < 2) {
            _Float16* th = wqkT_hi + (size_t)which * DMODEL * DMODEL;
            _Float16* tl = wqkT_lo + (size_t)which * DMODEL * DMODEL;
#pragma unroll
            for (int j = 0; j < 4; ++j) {
                float v = tile[tx][ty * 4 + j];
                size_t idx = (size_t)(c0 + ty * 4 + j) * DMODEL + r0 + tx;
                _Float16 h, l;
                split_val(v, h, l);
                th[idx] = h;
                tl[idx] = l;
            }
        } else {
#pragma unroll
            for (int j = 0; j < 4; ++j)
                wvT[(size_t)(c0 + ty * 4 + j) * DMODEL + r0 + tx] =
                    (_Float16)tile[tx][ty * 4 + j];
        }
    } else {
        const int t0 = (b - 3072) * 256 + threadIdx.x;
#pragma unroll
        for (int rep = 0; rep < 4; ++rep) {
            const size_t i = (size_t)t0 + (size_t)rep * 262144;
            floatx4 v = *(const floatx4*)(x + 4 * i);
            half4v h, l;
#pragma unroll
            for (int j = 0; j < 4; ++j) {
                _Float16 hh = (_Float16)v[j];
                _Float16 ll = (_Float16)(v[j] - (float)hh);
                h[j] = hh;
                l[j] = ll;
            }
            *(half4v*)(x_hi + 4 * i) = h;
            *(half4v*)(x_lo + 4 * i) = l;
        }
    }
}

// ---------------------------------------------------------------------------
// QK projection: 3-product split fp16 GEMM (16x16x32), tile 128x128, BK=32.
// C = (x_hi+x_lo) @ (wqk_hi+wqk_lo)^T, hi/lo outputs routed by column half
// at ldc=1024. R10-exact (standalone, no dead template args).
// ---------------------------------------------------------------------------
__global__ __launch_bounds__(256) void gemm_qkproj(
    const _Float16* __restrict__ Ahi, const _Float16* __restrict__ Alo,
    const _Float16* __restrict__ Bhi, const _Float16* __restrict__ Blo,
    _Float16* __restrict__ Chi, _Float16* __restrict__ Clo,
    _Float16* __restrict__ Chi2, _Float16* __restrict__ Clo2) {
    __shared__ _Float16 Ah[128][32];
    __shared__ _Float16 Al[128][32];
    __shared__ _Float16 Bh[128][32];
    __shared__ _Float16 Bl[128][32];

    const int tid = threadIdx.x;
    const int lane = tid & 63;
    const int w = tid >> 6;
    const int wm = (w >> 1) * 64;
    const int wn = (w & 1) * 64;

    const int rowA0 = blockIdx.y * 128;
    const int colB0 = blockIdx.x * 128;

    const int sr = lane >> 2;
    const int sc = lane & 3;
    const int r0 = w * 32 + sr;
    const int r1 = r0 + 16;
    const int cg0 = sc ^ ((r0 >> 1) & 3);
    const int cg1 = sc ^ ((r1 >> 1) & 3);

    const char* gp[8];
    gp[0] = (const char*)(Ahi + (size_t)(rowA0 + r0) * DMODEL) + cg0 * 16;
    gp[1] = (const char*)(Ahi + (size_t)(rowA0 + r1) * DMODEL) + cg1 * 16;
    gp[2] = (const char*)(Alo + (size_t)(rowA0 + r0) * DMODEL) + cg0 * 16;
    gp[3] = (const char*)(Alo + (size_t)(rowA0 + r1) * DMODEL) + cg1 * 16;
    gp[4] = (const char*)(Bhi + (size_t)(colB0 + r0) * DMODEL) + cg0 * 16;
    gp[5] = (const char*)(Bhi + (size_t)(colB0 + r1) * DMODEL) + cg1 * 16;
    gp[6] = (const char*)(Blo + (size_t)(colB0 + r0) * DMODEL) + cg0 * 16;
    gp[7] = (const char*)(Blo + (size_t)(colB0 + r1) * DMODEL) + cg1 * 16;

    _Float16* lp[8] = {
        &Ah[w * 32][0], &Ah[w * 32 + 16][0],
        &Al[w * 32][0], &Al[w * 32 + 16][0],
        &Bh[w * 32][0], &Bh[w * 32 + 16][0],
        &Bl[w * 32][0], &Bl[w * 32 + 16][0],
    };

    const int fm = lane & 15;
    const int fq = lane >> 4;
    const int ck = ((fq ^ ((fm >> 1) & 3)) * 8);

    floatx4 acc[4][4] = {};

    for (int k0 = 0; k0 < DMODEL; k0 += 32) {
#pragma unroll
        for (int t = 0; t < 8; ++t)
            __builtin_amdgcn_global_load_lds(
                (const __attribute__((address_space(1))) void*)gp[t],
                (__attribute__((address_space(3))) void*)lp[t], 16, 0, 0);
#pragma unroll
        for (int t = 0; t < 8; ++t) gp[t] += 64;
        __syncthreads();

        half8 ahv[4], bhv[4], blv[4], alv[4];
#pragma unroll
        for (int i = 0; i < 4; ++i) {
            ahv[i] = *(const half8*)&Ah[wm + i * 16 + fm][ck];
            bhv[i] = *(const half8*)&Bh[wn + i * 16 + fm][ck];
        }
#pragma unroll
        for (int i = 0; i < 4; ++i)
#pragma unroll
            for (int j = 0; j < 4; ++j)
                acc[i][j] = __builtin_amdgcn_mfma_f32_16x16x32_f16(ahv[i], bhv[j], acc[i][j], 0, 0, 0);
#pragma unroll
        for (int i = 0; i < 4; ++i) blv[i] = *(const half8*)&Bl[wn + i * 16 + fm][ck];
#pragma unroll
        for (int i = 0; i < 4; ++i)
#pragma unroll
            for (int j = 0; j < 4; ++j)
                acc[i][j] = __builtin_amdgcn_mfma_f32_16x16x32_f16(ahv[i], blv[j], acc[i][j], 0, 0, 0);
#pragma unroll
        for (int i = 0; i < 4; ++i) alv[i] = *(const half8*)&Al[wm + i * 16 + fm][ck];
#pragma unroll
        for (int i = 0; i < 4; ++i)
#pragma unroll
            for (int j = 0; j < 4; ++j)
                acc[i][j] = __builtin_amdgcn_mfma_f32_16x16x32_f16(alv[i], bhv[j], acc[i][j], 0, 0, 0);
        __syncthreads();
    }

    _Float16* dh = Chi;
    _Float16* dl = Clo;
    int cbase = colB0;
    if (colB0 >= 1024) { dh = Chi2; dl = Clo2; cbase = colB0 - 1024; }

#pragma unroll
    for (int i = 0; i < 4; ++i) {
        const int growb = rowA0 + wm + i * 16 + fq * 4;
#pragma unroll
        for (int j = 0; j < 4; ++j) {
            const int gcol = wn + j * 16 + fm;
#pragma unroll
            for (int r = 0; r < 4; ++r) {
                float v = acc[i][j][r];
                size_t idx = (size_t)(growb + r) * 1024 + cbase + gcol;
                _Float16 h, l;
                split_val(v, h, l);
                dh[idx] = h;
                dl[idx] = l;
            }
        }
    }
}

// ---------------------------------------------------------------------------
// Score GEMM using 32x32x16 MFMA (higher matrix-pipe ceiling: 2495 vs 2176
// TF µbench). Tile 128x128, BK=32, wave tile 64x64 = 2x2 subtiles of 32x32.
// A/B operand: lane holds [m=lane&31][k=(lane>>5)*8 + e]; C/D: col=lane&31,
// row=(reg&3)+8*(reg>>2)+4*(lane>>5). 3-product split precision.
// Tile-softmax epilogue: per row x 64-col wave span (t = colB0/64 + wn/64).
// ---------------------------------------------------------------------------
__global__ __launch_bounds__(256) void gemm_score(
    const _Float16* __restrict__ Ahi, const _Float16* __restrict__ Alo,
    const _Float16* __restrict__ Bhi, const _Float16* __restrict__ Blo,
    _Float16* __restrict__ Ph, float* __restrict__ Marr, float* __restrict__ Larr,
    float scale) {
    __shared__ _Float16 Ah[128][32];
    __shared__ _Float16 Al[128][32];
    __shared__ _Float16 Bh[128][32];
    __shared__ _Float16 Bl[128][32];

    const int tid = threadIdx.x;
    const int lane = tid & 63;
    const int w = tid >> 6;
    const int wm = (w >> 1) * 64;
    const int wn = (w & 1) * 64;

    const int rowA0 = blockIdx.y * 128;
    const int colB0 = blockIdx.x * 128;

    // ---- staging (identical to 16x16 version) ----
    const int sr = lane >> 2;
    const int sc = lane & 3;
    const int r0 = w * 32 + sr;
    const int r1 = r0 + 16;
    const int cg0 = sc ^ ((r0 >> 1) & 3);
    const int cg1 = sc ^ ((r1 >> 1) & 3);

    const char* gp[8];
    gp[0] = (const char*)(Ahi + (size_t)(rowA0 + r0) * DMODEL) + cg0 * 16;
    gp[1] = (const char*)(Ahi + (size_t)(rowA0 + r1) * DMODEL) + cg1 * 16;
    gp[2] = (const char*)(Alo + (size_t)(rowA0 + r0) * DMODEL) + cg0 * 16;
    gp[3] = (const char*)(Alo + (size_t)(rowA0 + r1) * DMODEL) + cg1 * 16;
    gp[4] = (const char*)(Bhi + (size_t)(colB0 + r0) * DMODEL) + cg0 * 16;
    gp[5] = (const char*)(Bhi + (size_t)(colB0 + r1) * DMODEL) + cg1 * 16;
    gp[6] = (const char*)(Blo + (size_t)(colB0 + r0) * DMODEL) + cg0 * 16;
    gp[7] = (const char*)(Blo + (size_t)(colB0 + r1) * DMODEL) + cg1 * 16;

    _Float16* lp[8] = {
        &Ah[w * 32][0], &Ah[w * 32 + 16][0],
        &Al[w * 32][0], &Al[w * 32 + 16][0],
        &Bh[w * 32][0], &Bh[w * 32 + 16][0],
        &Bl[w * 32][0], &Bl[w * 32 + 16][0],
    };

    // ---- 32x32 fragment geometry ----
    const int fm = lane & 31;          // row within 32x32 tile
    const int kh = lane >> 5;          // k-half selector (0/1)
    const int sw = (fm >> 1) & 3;      // row bank-swizzle
    // logical chunk for k-substep s (k = s*16 + kh*8): c = 2*s + kh
    const int off0 = ((0 + kh) ^ sw) * 8;   // s=0
    const int off1 = ((2 + kh) ^ sw) * 8;   // s=1

    floatx16 acc[2][2] = {};

    for (int k0 = 0; k0 < DMODEL; k0 += 32) {
#pragma unroll
        for (int t = 0; t < 8; ++t)
            __builtin_amdgcn_global_load_lds(
                (const __attribute__((address_space(1))) void*)gp[t],
                (__attribute__((address_space(3))) void*)lp[t], 16, 0, 0);
#pragma unroll
        for (int t = 0; t < 8; ++t) gp[t] += 64;
        __syncthreads();

        half8 ah[2][2], bh[2][2], bl[2][2], al[2][2];   // [subtile][ksub]
#pragma unroll
        for (int i = 0; i < 2; ++i) {
            ah[i][0] = *(const half8*)&Ah[wm + i * 32 + fm][off0];
            ah[i][1] = *(const half8*)&Ah[wm + i * 32 + fm][off1];
            bh[i][0] = *(const half8*)&Bh[wn + i * 32 + fm][off0];
            bh[i][1] = *(const half8*)&Bh[wn + i * 32 + fm][off1];
        }
#pragma unroll
        for (int s = 0; s < 2; ++s)
#pragma unroll
            for (int i = 0; i < 2; ++i)
#pragma unroll
                for (int j = 0; j < 2; ++j)
                    acc[i][j] = __builtin_amdgcn_mfma_f32_32x32x16_f16(ah[i][s], bh[j][s], acc[i][j], 0, 0, 0);
#pragma unroll
        for (int i = 0; i < 2; ++i) {
            bl[i][0] = *(const half8*)&Bl[wn + i * 32 + fm][off0];
            bl[i][1] = *(const half8*)&Bl[wn + i * 32 + fm][off1];
        }
#pragma unroll
        for (int s = 0; s < 2; ++s)
#pragma unroll
            for (int i = 0; i < 2; ++i)
#pragma unroll
                for (int j = 0; j < 2; ++j)
                    acc[i][j] = __builtin_amdgcn_mfma_f32_32x32x16_f16(ah[i][s], bl[j][s], acc[i][j], 0, 0, 0);
#pragma unroll
        for (int i = 0; i < 2; ++i) {
            al[i][0] = *(const half8*)&Al[wm + i * 32 + fm][off0];
            al[i][1] = *(const half8*)&Al[wm + i * 32 + fm][off1];
        }
#pragma unroll
        for (int s = 0; s < 2; ++s)
#pragma unroll
            for (int i = 0; i < 2; ++i)
#pragma unroll
                for (int j = 0; j < 2; ++j)
                    acc[i][j] = __builtin_amdgcn_mfma_f32_32x32x16_f16(al[i][s], bh[j][s], acc[i][j], 0, 0, 0);
        __syncthreads();
    }

    // ---- tile-softmax epilogue ----
    // Each lane holds, per (i, reg): row = rowA0+wm+i*32+(reg&3)+8*(reg>>2)+4*kh,
    // cols colB0+wn+{fm, 32+fm}. The 32 lanes of a k-half hold the same row;
    // xor-shuffles 1..16 stay within the half.
    const int tprime = (colB0 >> 6) + (wn >> 6);
    const int colbase = colB0 + wn;
#pragma unroll
    for (int i = 0; i < 2; ++i) {
#pragma unroll
        for (int r = 0; r < 16; ++r) {
            const int grow = rowA0 + wm + i * 32 + (r & 3) + 8 * (r >> 2) + 4 * kh;
            float s0 = acc[i][0][r] * scale;
            float s1 = acc[i][1][r] * scale;
            float mx = fmaxf(s0, s1);
            mx = fmaxf(mx, __shfl_xor(mx, 1));
            mx = fmaxf(mx, __shfl_xor(mx, 2));
            mx = fmaxf(mx, __shfl_xor(mx, 4));
            mx = fmaxf(mx, __shfl_xor(mx, 8));
            mx = fmaxf(mx, __shfl_xor(mx, 16));
            float p0 = __expf(s0 - mx);
            float p1 = __expf(s1 - mx);
            float sum = p0 + p1;
            sum += __shfl_xor(sum, 1);
            sum += __shfl_xor(sum, 2);
            sum += __shfl_xor(sum, 4);
            sum += __shfl_xor(sum, 8);
            sum += __shfl_xor(sum, 16);
            _Float16* prow = Ph + (size_t)grow * SEQ + colbase + fm;
            prow[0]  = (_Float16)p0;
            prow[32] = (_Float16)p1;
            if (fm == 0) {
                Marr[(size_t)grow * 64 + tprime] = mx;
                Larr[(size_t)grow * 64 + tprime] = sum;
            }
        }
    }
}

// ---------------------------------------------------------------------------
// Per-row finalize: wave 0 computes m*, L, c_t = e^(m_t-m*)/L into LDS;
// all 256 threads rescale the row's 4096 fp16 P values in place.
// ---------------------------------------------------------------------------
__global__ __launch_bounds__(256) void reduce_scale(const float* __restrict__ Marr,
                                                    const float* __restrict__ Larr,
                                                    _Float16* __restrict__ P) {
    __shared__ float c_tab[64];
    const int tid = threadIdx.x;
    const int row = blockIdx.x;

    if (tid < 64) {
        float mt = Marr[(size_t)row * 64 + tid];
        float lt = Larr[(size_t)row * 64 + tid];
        float m = mt;
#pragma unroll
        for (int off = 32; off > 0; off >>= 1) m = fmaxf(m, __shfl_xor(m, off));
        float contrib = lt * __expf(mt - m);
        float L = contrib;
#pragma unroll
        for (int off = 32; off > 0; off >>= 1) L += __shfl_xor(L, off);
        c_tab[tid] = __expf(mt - m) / L;
    }
    __syncthreads();

    _Float16* prow = P + (size_t)row * SEQ;
#pragma unroll
    for (int i = 0; i < 4; ++i) {
        const int col = i * 1024 + (tid << 2);
        const _Float16 c = (_Float16)c_tab[col >> 6];
        half4v v = *(const half4v*)(prow + col);
        v[0] *= c; v[1] *= c; v[2] *= c; v[3] *= c;
        *(half4v*)(prow + col) = v;
    }
}

// ---------------------------------------------------------------------------
// Plain fp16 MFMA GEMM, tile 128x64 (16x16x32): V-projection and PV.
// OUT_HALF==0: fp32 out. OUT_HALF==1: fp16 out. R10-exact.
// ---------------------------------------------------------------------------
template <int OUT_HALF>
__global__ __launch_bounds__(256) void gemm_h16_n64(
    const _Float16* __restrict__ A, int lda,
    const _Float16* __restrict__ B, int ldb,
    float* __restrict__ Cf, _Float16* __restrict__ Ch,
    int N, int K) {
    __shared__ _Float16 Ah[128][32];
    __shared__ _Float16 Bh[64][32];

    const int tid = threadIdx.x;
    const int lane = tid & 63;
    const int w = tid >> 6;
    const int wm = (w >> 1) * 64;
    const int wn = (w & 1) * 32;

    const int rowA0 = blockIdx.y * 128;
    const int colB0 = blockIdx.x * 64;

    const int sr = lane >> 2;
    const int sc = lane & 3;
    const int ra0 = w * 32 + sr;
    const int ra1 = ra0 + 16;
    const int rb0 = w * 16 + sr;
    const int cga0 = sc ^ ((ra0 >> 1) & 3);
    const int cga1 = sc ^ ((ra1 >> 1) & 3);
    const int cgb0 = sc ^ ((rb0 >> 1) & 3);

    const char* gp[3];
    gp[0] = (const char*)(A + (size_t)(rowA0 + ra0) * lda) + cga0 * 16;
    gp[1] = (const char*)(A + (size_t)(rowA0 + ra1) * lda) + cga1 * 16;
    gp[2] = (const char*)(B + (size_t)(colB0 + rb0) * ldb) + cgb0 * 16;

    _Float16* lp[3] = {
        &Ah[w * 32][0], &Ah[w * 32 + 16][0],
        &Bh[w * 16][0],
    };

    const int fm = lane & 15;
    const int fq = lane >> 4;
    const int ck = ((fq ^ ((fm >> 1) & 3)) * 8);

    floatx4 acc[4][2] = {};

    for (int k0 = 0; k0 < K; k0 += 32) {
#pragma unroll
        for (int t = 0; t < 3; ++t)
            __builtin_amdgcn_global_load_lds(
                (const __attribute__((address_space(1))) void*)gp[t],
                (__attribute__((address_space(3))) void*)lp[t], 16, 0, 0);
#pragma unroll
        for (int t = 0; t < 3; ++t) gp[t] += 64;
        __syncthreads();

        half8 av[4], bv[2];
#pragma unroll
        for (int i = 0; i < 4; ++i)
            av[i] = *(const half8*)&Ah[wm + i * 16 + fm][ck];
#pragma unroll
        for (int j = 0; j < 2; ++j)
            bv[j] = *(const half8*)&Bh[wn + j * 16 + fm][ck];
#pragma unroll
        for (int i = 0; i < 4; ++i)
#pragma unroll
            for (int j = 0; j < 2; ++j)
                acc[i][j] = __builtin_amdgcn_mfma_f32_16x16x32_f16(av[i], bv[j], acc[i][j], 0, 0, 0);
        __syncthreads();
    }

#pragma unroll
    for (int i = 0; i < 4; ++i) {
        const int growb = rowA0 + wm + i * 16 + fq * 4;
#pragma unroll
        for (int j = 0; j < 2; ++j) {
            const int gcol = colB0 + wn + j * 16 + fm;
#pragma unroll
            for (int r = 0; r < 4; ++r) {
                float v = acc[i][j][r];
                size_t idx = (size_t)(growb + r) * N + gcol;
                if (OUT_HALF) Ch[idx] = (_Float16)v;
                else          Cf[idx] = v;
            }
        }
    }
}

// ---------------------------------------------------------------------------
// Workspace layout (104 MB used):
//  [0,32M)   P fp16 [4096][4096] (region reused: x_hi [0,8M), x_lo [8,16M),
//            wqkT_hi [16,20M), wqkT_lo [20,24M), wvT [24,26M) all dead
//            before the score kernel writes P)
//  [32,33M)  Marr fp32 [4096][64]   [33,34M) Larr fp32 [4096][64]
//  [64,72M)  Q_hi  [72,80M) Q_lo  [80,88M) K_hi  [88,96M) K_lo  (ldc=1024)
//  [96,104M) VT fp16 [1024][4096]
// ---------------------------------------------------------------------------
extern "C" void kernel_launch(void* const* d_in, const int* in_sizes, int n_in,
                              void* d_out, int out_size, void* d_ws, size_t ws_size,
                              hipStream_t stream) {
    const float* x  = (const float*)d_in[0];
    const float* wq = (const float*)d_in[1];
    const float* wk = (const float*)d_in[2];
    const float* wv = (const float*)d_in[3];
    float* out = (float*)d_out;

    char* base = (char*)d_ws;
    const size_t MB = 1u << 20;
    _Float16* P       = (_Float16*)base;               // [4096][4096]
    _Float16* x_hi    = (_Float16*)(base + 0 * MB);
    _Float16* x_lo    = (_Float16*)(base + 8 * MB);
    _Float16* wqkT_hi = (_Float16*)(base + 16 * MB);   // [2048][1024]
    _Float16* wqkT_lo = (_Float16*)(base + 20 * MB);
    _Float16* wvT     = (_Float16*)(base + 24 * MB);   // [1024][1024]
    float*    Marr    = (float*)(base + 32 * MB);
    float*    Larr    = (float*)(base + 33 * MB);
    _Float16* Q_hi    = (_Float16*)(base + 64 * MB);   // [4096][1024]
    _Float16* Q_lo    = (_Float16*)(base + 72 * MB);
    _Float16* K_hi    = (_Float16*)(base + 80 * MB);
    _Float16* K_lo    = (_Float16*)(base + 88 * MB);
    _Float16* VT      = (_Float16*)(base + 96 * MB);   // [1024][4096]

    // 1) fused prep
    prep<<<4096, 256, 0, stream>>>(x, wq, wk, wv, x_hi, x_lo, wqkT_hi, wqkT_lo, wvT);

    // 2) QK projection (split outputs, ldc=1024)
    dim3 gqk(2048 / 128, SEQ / 128);   // (16,32)
    gemm_qkproj<<<gqk, 256, 0, stream>>>(x_hi, x_lo, wqkT_hi, wqkT_lo,
                                         Q_hi, Q_lo, K_hi, K_lo);
    // V^T = wv^T @ x^T, plain fp16, tile 128x64
    dim3 gvt(SEQ / 64, DMODEL / 128);  // (64,8)
    gemm_h16_n64<1><<<gvt, 256, 0, stream>>>(wvT, DMODEL, x_hi, DMODEL,
                                             nullptr, VT, SEQ, DMODEL);

    // 3) scores + tile-softmax (32x32x16 MFMA): P = exp(QK^T/32 - m_t)
    dim3 gs(SEQ / 128, SEQ / 128);     // (32,32)
    gemm_score<<<gs, 256, 0, stream>>>(Q_hi, Q_lo, K_hi, K_lo,
                                       P, Marr, Larr, 1.0f / 32.0f);

    // 4) finalize: P *= c_t(row)  (in place, exact softmax)
    reduce_scale<<<SEQ, 256, 0, stream>>>(Marr, Larr, P);

    // 5) out = P @ V, plain fp16
    dim3 go(DMODEL / 64, SEQ / 128);   // (16,32)
    gemm_h16_n64<0><<<go, 256, 0, stream>>>(P, SEQ, VT, SEQ,
                                            out, nullptr, DMODEL, SEQ);
}

// Round 14
// 349.281 us; speedup vs baseline: 1.0891x; 1.0891x over previous
//
#include <hip/hip_runtime.h>
#include <hip/hip_fp16.h>
#include <math.h>

#define SEQ    4096
#define DMODEL 1024

typedef _Float16 half8   __attribute__((ext_vector_type(8)));
typedef _Float16 half4v  __attribute__((ext_vector_type(4)));
typedef float    floatx4 __attribute__((ext_vector_type(4)));

__device__ inline void split_val(float v, _Float16& h, _Float16& l) {
    _Float16 hh = (_Float16)v;
    h = hh;
    l = (_Float16)(v - (float)hh);
}

// ---------------------------------------------------------------------------
// Fused prep: blocks 0..3071 transpose wq/wk/wv (32x32 tiles); blocks
// 3072..4095 split x into hi/lo fp16 (4 float4 per thread = full x).
// ---------------------------------------------------------------------------
__global__ __launch_bounds__(256) void prep(const float* __restrict__ x,
                                            const float* __restrict__ wq,
                                            const float* __restrict__ wk,
                                            const float* __restrict__ wv,
                                            _Float16* __restrict__ x_hi,
                                            _Float16* __restrict__ x_lo,
                                            _Float16* __restrict__ wqkT_hi,
                                            _Float16* __restrict__ wqkT_lo,
                                            _Float16* __restrict__ wvT) {
    __shared__ float tile[32][33];
    const int b = blockIdx.x;
    if (b < 3072) {
        const int which = b >> 10;           // 0=wq 1=wk 2=wv
        const int bb = b & 1023;
        const int c0 = (bb & 31) * 32;
        const int r0 = (bb >> 5) * 32;
        const float* w = (which == 0) ? wq : (which == 1) ? wk : wv;
        const int tx = threadIdx.x & 31, ty = threadIdx.x >> 5;
#pragma unroll
        for (int j = 0; j < 4; ++j)
            tile[ty * 4 + j][tx] = w[(size_t)(r0 + ty * 4 + j) * DMODEL + c0 + tx];
        __syncthreads();
        if (which < 2) {
            _Float16* th = wqkT_hi + (size_t)which * DMODEL * DMODEL;
            _Float16* tl = wqkT_lo + (size_t)which * DMODEL * DMODEL;
#pragma unroll
            for (int j = 0; j < 4; ++j) {
                float v = tile[tx][ty * 4 + j];
                size_t idx = (size_t)(c0 + ty * 4 + j) * DMODEL + r0 + tx;
                _Float16 h, l;
                split_val(v, h, l);
                th[idx] = h;
                tl[idx] = l;
            }
        } else {
#pragma unroll
            for (int j = 0; j < 4; ++j)
                wvT[(size_t)(c0 + ty * 4 + j) * DMODEL + r0 + tx] =
                    (_Float16)tile[tx][ty * 4 + j];
        }
    } else {
        const int t0 = (b - 3072) * 256 + threadIdx.x;
#pragma unroll
        for (int rep = 0; rep < 4; ++rep) {
            const size_t i = (size_t)t0 + (size_t)rep * 262144;
            floatx4 v = *(const floatx4*)(x + 4 * i);
            half4v h, l;
#pragma unroll
            for (int j = 0; j < 4; ++j) {
                _Float16 hh = (_Float16)v[j];
                _Float16 ll = (_Float16)(v[j] - (float)hh);
                h[j] = hh;
                l[j] = ll;
            }
            *(half4v*)(x_hi + 4 * i) = h;
            *(half4v*)(x_lo + 4 * i) = l;
        }
    }
}

// ---------------------------------------------------------------------------
// QK projection: 3-product split fp16 GEMM (16x16x32), tile 128x128, BK=32.
// C = (x_hi+x_lo) @ (wqk_hi+wqk_lo)^T, hi/lo outputs routed by column half
// at ldc=1024.
// ---------------------------------------------------------------------------
__global__ __launch_bounds__(256) void gemm_qkproj(
    const _Float16* __restrict__ Ahi, const _Float16* __restrict__ Alo,
    const _Float16* __restrict__ Bhi, const _Float16* __restrict__ Blo,
    _Float16* __restrict__ Chi, _Float16* __restrict__ Clo,
    _Float16* __restrict__ Chi2, _Float16* __restrict__ Clo2) {
    __shared__ _Float16 Ah[128][32];
    __shared__ _Float16 Al[128][32];
    __shared__ _Float16 Bh[128][32];
    __shared__ _Float16 Bl[128][32];

    const int tid = threadIdx.x;
    const int lane = tid & 63;
    const int w = tid >> 6;
    const int wm = (w >> 1) * 64;
    const int wn = (w & 1) * 64;

    const int rowA0 = blockIdx.y * 128;
    const int colB0 = blockIdx.x * 128;

    const int sr = lane >> 2;
    const int sc = lane & 3;
    const int r0 = w * 32 + sr;
    const int r1 = r0 + 16;
    const int cg0 = sc ^ ((r0 >> 1) & 3);
    const int cg1 = sc ^ ((r1 >> 1) & 3);

    const char* gp[8];
    gp[0] = (const char*)(Ahi + (size_t)(rowA0 + r0) * DMODEL) + cg0 * 16;
    gp[1] = (const char*)(Ahi + (size_t)(rowA0 + r1) * DMODEL) + cg1 * 16;
    gp[2] = (const char*)(Alo + (size_t)(rowA0 + r0) * DMODEL) + cg0 * 16;
    gp[3] = (const char*)(Alo + (size_t)(rowA0 + r1) * DMODEL) + cg1 * 16;
    gp[4] = (const char*)(Bhi + (size_t)(colB0 + r0) * DMODEL) + cg0 * 16;
    gp[5] = (const char*)(Bhi + (size_t)(colB0 + r1) * DMODEL) + cg1 * 16;
    gp[6] = (const char*)(Blo + (size_t)(colB0 + r0) * DMODEL) + cg0 * 16;
    gp[7] = (const char*)(Blo + (size_t)(colB0 + r1) * DMODEL) + cg1 * 16;

    _Float16* lp[8] = {
        &Ah[w * 32][0], &Ah[w * 32 + 16][0],
        &Al[w * 32][0], &Al[w * 32 + 16][0],
        &Bh[w * 32][0], &Bh[w * 32 + 16][0],
        &Bl[w * 32][0], &Bl[w * 32 + 16][0],
    };

    const int fm = lane & 15;
    const int fq = lane >> 4;
    const int ck = ((fq ^ ((fm >> 1) & 3)) * 8);

    floatx4 acc[4][4] = {};

    for (int k0 = 0; k0 < DMODEL; k0 += 32) {
#pragma unroll
        for (int t = 0; t < 8; ++t)
            __builtin_amdgcn_global_load_lds(
                (const __attribute__((address_space(1))) void*)gp[t],
                (__attribute__((address_space(3))) void*)lp[t], 16, 0, 0);
#pragma unroll
        for (int t = 0; t < 8; ++t) gp[t] += 64;
        __syncthreads();

        half8 ahv[4], bhv[4], blv[4], alv[4];
#pragma unroll
        for (int i = 0; i < 4; ++i) {
            ahv[i] = *(const half8*)&Ah[wm + i * 16 + fm][ck];
            bhv[i] = *(const half8*)&Bh[wn + i * 16 + fm][ck];
        }
#pragma unroll
        for (int i = 0; i < 4; ++i)
#pragma unroll
            for (int j = 0; j < 4; ++j)
                acc[i][j] = __builtin_amdgcn_mfma_f32_16x16x32_f16(ahv[i], bhv[j], acc[i][j], 0, 0, 0);
#pragma unroll
        for (int i = 0; i < 4; ++i) blv[i] = *(const half8*)&Bl[wn + i * 16 + fm][ck];
#pragma unroll
        for (int i = 0; i < 4; ++i)
#pragma unroll
            for (int j = 0; j < 4; ++j)
                acc[i][j] = __builtin_amdgcn_mfma_f32_16x16x32_f16(ahv[i], blv[j], acc[i][j], 0, 0, 0);
#pragma unroll
        for (int i = 0; i < 4; ++i) alv[i] = *(const half8*)&Al[wm + i * 16 + fm][ck];
#pragma unroll
        for (int i = 0; i < 4; ++i)
#pragma unroll
            for (int j = 0; j < 4; ++j)
                acc[i][j] = __builtin_amdgcn_mfma_f32_16x16x32_f16(alv[i], bhv[j], acc[i][j], 0, 0, 0);
        __syncthreads();
    }

    _Float16* dh = Chi;
    _Float16* dl = Clo;
    int cbase = colB0;
    if (colB0 >= 1024) { dh = Chi2; dl = Clo2; cbase = colB0 - 1024; }

#pragma unroll
    for (int i = 0; i < 4; ++i) {
        const int growb = rowA0 + wm + i * 16 + fq * 4;
#pragma unroll
        for (int j = 0; j < 4; ++j) {
            const int gcol = wn + j * 16 + fm;
#pragma unroll
            for (int r = 0; r < 4; ++r) {
                float v = acc[i][j][r];
                size_t idx = (size_t)(growb + r) * 1024 + cbase + gcol;
                _Float16 h, l;
                split_val(v, h, l);
                dh[idx] = h;
                dl[idx] = l;
            }
        }
    }
}

// ---------------------------------------------------------------------------
// Score GEMM (16x16x32, 3-product split, 128x128 tile, BK=32) with
// tile-softmax epilogue: per row x 64-col wave span (t = colB0/64 + wn/64):
// m_t = span max, P = exp(s - m_t) fp16 -> Ph, (m_t, sum) -> Marr/Larr.
// Measured 119.7 us, SQ_LDS_BANK_CONFLICT = 0 (R12).
// ---------------------------------------------------------------------------
__global__ __launch_bounds__(256) void gemm_score(
    const _Float16* __restrict__ Ahi, const _Float16* __restrict__ Alo,
    const _Float16* __restrict__ Bhi, const _Float16* __restrict__ Blo,
    _Float16* __restrict__ Ph, float* __restrict__ Marr, float* __restrict__ Larr,
    float scale) {
    __shared__ _Float16 Ah[128][32];
    __shared__ _Float16 Al[128][32];
    __shared__ _Float16 Bh[128][32];
    __shared__ _Float16 Bl[128][32];

    const int tid = threadIdx.x;
    const int lane = tid & 63;
    const int w = tid >> 6;
    const int wm = (w >> 1) * 64;
    const int wn = (w & 1) * 64;

    const int rowA0 = blockIdx.y * 128;
    const int colB0 = blockIdx.x * 128;

    const int sr = lane >> 2;
    const int sc = lane & 3;
    const int r0 = w * 32 + sr;
    const int r1 = r0 + 16;
    const int cg0 = sc ^ ((r0 >> 1) & 3);
    const int cg1 = sc ^ ((r1 >> 1) & 3);

    const char* gp[8];
    gp[0] = (const char*)(Ahi + (size_t)(rowA0 + r0) * DMODEL) + cg0 * 16;
    gp[1] = (const char*)(Ahi + (size_t)(rowA0 + r1) * DMODEL) + cg1 * 16;
    gp[2] = (const char*)(Alo + (size_t)(rowA0 + r0) * DMODEL) + cg0 * 16;
    gp[3] = (const char*)(Alo + (size_t)(rowA0 + r1) * DMODEL) + cg1 * 16;
    gp[4] = (const char*)(Bhi + (size_t)(colB0 + r0) * DMODEL) + cg0 * 16;
    gp[5] = (const char*)(Bhi + (size_t)(colB0 + r1) * DMODEL) + cg1 * 16;
    gp[6] = (const char*)(Blo + (size_t)(colB0 + r0) * DMODEL) + cg0 * 16;
    gp[7] = (const char*)(Blo + (size_t)(colB0 + r1) * DMODEL) + cg1 * 16;

    _Float16* lp[8] = {
        &Ah[w * 32][0], &Ah[w * 32 + 16][0],
        &Al[w * 32][0], &Al[w * 32 + 16][0],
        &Bh[w * 32][0], &Bh[w * 32 + 16][0],
        &Bl[w * 32][0], &Bl[w * 32 + 16][0],
    };

    const int fm = lane & 15;
    const int fq = lane >> 4;
    const int ck = ((fq ^ ((fm >> 1) & 3)) * 8);

    floatx4 acc[4][4] = {};

    for (int k0 = 0; k0 < DMODEL; k0 += 32) {
#pragma unroll
        for (int t = 0; t < 8; ++t)
            __builtin_amdgcn_global_load_lds(
                (const __attribute__((address_space(1))) void*)gp[t],
                (__attribute__((address_space(3))) void*)lp[t], 16, 0, 0);
#pragma unroll
        for (int t = 0; t < 8; ++t) gp[t] += 64;
        __syncthreads();

        half8 ahv[4], bhv[4], blv[4], alv[4];
#pragma unroll
        for (int i = 0; i < 4; ++i) {
            ahv[i] = *(const half8*)&Ah[wm + i * 16 + fm][ck];
            bhv[i] = *(const half8*)&Bh[wn + i * 16 + fm][ck];
        }
#pragma unroll
        for (int i = 0; i < 4; ++i)
#pragma unroll
            for (int j = 0; j < 4; ++j)
                acc[i][j] = __builtin_amdgcn_mfma_f32_16x16x32_f16(ahv[i], bhv[j], acc[i][j], 0, 0, 0);
#pragma unroll
        for (int i = 0; i < 4; ++i) blv[i] = *(const half8*)&Bl[wn + i * 16 + fm][ck];
#pragma unroll
        for (int i = 0; i < 4; ++i)
#pragma unroll
            for (int j = 0; j < 4; ++j)
                acc[i][j] = __builtin_amdgcn_mfma_f32_16x16x32_f16(ahv[i], blv[j], acc[i][j], 0, 0, 0);
#pragma unroll
        for (int i = 0; i < 4; ++i) alv[i] = *(const half8*)&Al[wm + i * 16 + fm][ck];
#pragma unroll
        for (int i = 0; i < 4; ++i)
#pragma unroll
            for (int j = 0; j < 4; ++j)
                acc[i][j] = __builtin_amdgcn_mfma_f32_16x16x32_f16(alv[i], bhv[j], acc[i][j], 0, 0, 0);
        __syncthreads();
    }

    const int tprime = (colB0 >> 6) + (wn >> 6);
#pragma unroll
    for (int i = 0; i < 4; ++i) {
#pragma unroll
        for (int r = 0; r < 4; ++r) {
            const int grow = rowA0 + wm + i * 16 + fq * 4 + r;
            float s0 = acc[i][0][r] * scale;
            float s1 = acc[i][1][r] * scale;
            float s2 = acc[i][2][r] * scale;
            float s3 = acc[i][3][r] * scale;
            float mx = fmaxf(fmaxf(s0, s1), fmaxf(s2, s3));
            mx = fmaxf(mx, __shfl_xor(mx, 1));
            mx = fmaxf(mx, __shfl_xor(mx, 2));
            mx = fmaxf(mx, __shfl_xor(mx, 4));
            mx = fmaxf(mx, __shfl_xor(mx, 8));
            float p0 = __expf(s0 - mx);
            float p1 = __expf(s1 - mx);
            float p2 = __expf(s2 - mx);
            float p3 = __expf(s3 - mx);
            float sum = p0 + p1 + p2 + p3;
            sum += __shfl_xor(sum, 1);
            sum += __shfl_xor(sum, 2);
            sum += __shfl_xor(sum, 4);
            sum += __shfl_xor(sum, 8);
            _Float16* prow = Ph + (size_t)grow * SEQ + colB0 + wn + fm;
            prow[0]  = (_Float16)p0;
            prow[16] = (_Float16)p1;
            prow[32] = (_Float16)p2;
            prow[48] = (_Float16)p3;
            if (fm == 0) {
                Marr[(size_t)grow * 64 + tprime] = mx;
                Larr[(size_t)grow * 64 + tprime] = sum;
            }
        }
    }
}

// ---------------------------------------------------------------------------
// Per-row finalize: wave 0 computes m*, L, c_t = e^(m_t-m*)/L into LDS;
// all 256 threads rescale the row's 4096 fp16 P values in place.
// ---------------------------------------------------------------------------
__global__ __launch_bounds__(256) void reduce_scale(const float* __restrict__ Marr,
                                                    const float* __restrict__ Larr,
                                                    _Float16* __restrict__ P) {
    __shared__ float c_tab[64];
    const int tid = threadIdx.x;
    const int row = blockIdx.x;

    if (tid < 64) {
        float mt = Marr[(size_t)row * 64 + tid];
        float lt = Larr[(size_t)row * 64 + tid];
        float m = mt;
#pragma unroll
        for (int off = 32; off > 0; off >>= 1) m = fmaxf(m, __shfl_xor(m, off));
        float contrib = lt * __expf(mt - m);
        float L = contrib;
#pragma unroll
        for (int off = 32; off > 0; off >>= 1) L += __shfl_xor(L, off);
        c_tab[tid] = __expf(mt - m) / L;
    }
    __syncthreads();

    _Float16* prow = P + (size_t)row * SEQ;
#pragma unroll
    for (int i = 0; i < 4; ++i) {
        const int col = i * 1024 + (tid << 2);
        const _Float16 c = (_Float16)c_tab[col >> 6];
        half4v v = *(const half4v*)(prow + col);
        v[0] *= c; v[1] *= c; v[2] *= c; v[3] *= c;
        *(half4v*)(prow + col) = v;
    }
}

// ---------------------------------------------------------------------------
// Plain fp16 MFMA GEMM, tile 128x64 (16x16x32): V-projection and PV.
// OUT_HALF==0: fp32 out. OUT_HALF==1: fp16 out.
// ---------------------------------------------------------------------------
template <int OUT_HALF>
__global__ __launch_bounds__(256) void gemm_h16_n64(
    const _Float16* __restrict__ A, int lda,
    const _Float16* __restrict__ B, int ldb,
    float* __restrict__ Cf, _Float16* __restrict__ Ch,
    int N, int K) {
    __shared__ _Float16 Ah[128][32];
    __shared__ _Float16 Bh[64][32];

    const int tid = threadIdx.x;
    const int lane = tid & 63;
    const int w = tid >> 6;
    const int wm = (w >> 1) * 64;
    const int wn = (w & 1) * 32;

    const int rowA0 = blockIdx.y * 128;
    const int colB0 = blockIdx.x * 64;

    const int sr = lane >> 2;
    const int sc = lane & 3;
    const int ra0 = w * 32 + sr;
    const int ra1 = ra0 + 16;
    const int rb0 = w * 16 + sr;
    const int cga0 = sc ^ ((ra0 >> 1) & 3);
    const int cga1 = sc ^ ((ra1 >> 1) & 3);
    const int cgb0 = sc ^ ((rb0 >> 1) & 3);

    const char* gp[3];
    gp[0] = (const char*)(A + (size_t)(rowA0 + ra0) * lda) + cga0 * 16;
    gp[1] = (const char*)(A + (size_t)(rowA0 + ra1) * lda) + cga1 * 16;
    gp[2] = (const char*)(B + (size_t)(colB0 + rb0) * ldb) + cgb0 * 16;

    _Float16* lp[3] = {
        &Ah[w * 32][0], &Ah[w * 32 + 16][0],
        &Bh[w * 16][0],
    };

    const int fm = lane & 15;
    const int fq = lane >> 4;
    const int ck = ((fq ^ ((fm >> 1) & 3)) * 8);

    floatx4 acc[4][2] = {};

    for (int k0 = 0; k0 < K; k0 += 32) {
#pragma unroll
        for (int t = 0; t < 3; ++t)
            __builtin_amdgcn_global_load_lds(
                (const __attribute__((address_space(1))) void*)gp[t],
                (__attribute__((address_space(3))) void*)lp[t], 16, 0, 0);
#pragma unroll
        for (int t = 0; t < 3; ++t) gp[t] += 64;
        __syncthreads();

        half8 av[4], bv[2];
#pragma unroll
        for (int i = 0; i < 4; ++i)
            av[i] = *(const half8*)&Ah[wm + i * 16 + fm][ck];
#pragma unroll
        for (int j = 0; j < 2; ++j)
            bv[j] = *(const half8*)&Bh[wn + j * 16 + fm][ck];
#pragma unroll
        for (int i = 0; i < 4; ++i)
#pragma unroll
            for (int j = 0; j < 2; ++j)
                acc[i][j] = __builtin_amdgcn_mfma_f32_16x16x32_f16(av[i], bv[j], acc[i][j], 0, 0, 0);
        __syncthreads();
    }

#pragma unroll
    for (int i = 0; i < 4; ++i) {
        const int growb = rowA0 + wm + i * 16 + fq * 4;
#pragma unroll
        for (int j = 0; j < 2; ++j) {
            const int gcol = colB0 + wn + j * 16 + fm;
#pragma unroll
            for (int r = 0; r < 4; ++r) {
                float v = acc[i][j][r];
                size_t idx = (size_t)(growb + r) * N + gcol;
                if (OUT_HALF) Ch[idx] = (_Float16)v;
                else          Cf[idx] = v;
            }
        }
    }
}

// ---------------------------------------------------------------------------
// Workspace layout (104 MB used):
//  [0,32M)   P fp16 [4096][4096] (region reused: x_hi [0,8M), x_lo [8,16M),
//            wqkT_hi [16,20M), wqkT_lo [20,24M), wvT [24,26M) all dead
//            before the score kernel writes P)
//  [32,33M)  Marr fp32 [4096][64]   [33,34M) Larr fp32 [4096][64]
//  [64,72M)  Q_hi  [72,80M) Q_lo  [80,88M) K_hi  [88,96M) K_lo  (ldc=1024)
//  [96,104M) VT fp16 [1024][4096]
// ---------------------------------------------------------------------------
extern "C" void kernel_launch(void* const* d_in, const int* in_sizes, int n_in,
                              void* d_out, int out_size, void* d_ws, size_t ws_size,
                              hipStream_t stream) {
    const float* x  = (const float*)d_in[0];
    const float* wq = (const float*)d_in[1];
    const float* wk = (const float*)d_in[2];
    const float* wv = (const float*)d_in[3];
    float* out = (float*)d_out;

    char* base = (char*)d_ws;
    const size_t MB = 1u << 20;
    _Float16* P       = (_Float16*)base;               // [4096][4096]
    _Float16* x_hi    = (_Float16*)(base + 0 * MB);
    _Float16* x_lo    = (_Float16*)(base + 8 * MB);
    _Float16* wqkT_hi = (_Float16*)(base + 16 * MB);   // [2048][1024]
    _Float16* wqkT_lo = (_Float16*)(base + 20 * MB);
    _Float16* wvT     = (_Float16*)(base + 24 * MB);   // [1024][1024]
    float*    Marr    = (float*)(base + 32 * MB);
    float*    Larr    = (float*)(base + 33 * MB);
    _Float16* Q_hi    = (_Float16*)(base + 64 * MB);   // [4096][1024]
    _Float16* Q_lo    = (_Float16*)(base + 72 * MB);
    _Float16* K_hi    = (_Float16*)(base + 80 * MB);
    _Float16* K_lo    = (_Float16*)(base + 88 * MB);
    _Float16* VT      = (_Float16*)(base + 96 * MB);   // [1024][4096]

    // 1) fused prep
    prep<<<4096, 256, 0, stream>>>(x, wq, wk, wv, x_hi, x_lo, wqkT_hi, wqkT_lo, wvT);

    // 2) QK projection (split outputs, ldc=1024)
    dim3 gqk(2048 / 128, SEQ / 128);   // (16,32)
    gemm_qkproj<<<gqk, 256, 0, stream>>>(x_hi, x_lo, wqkT_hi, wqkT_lo,
                                         Q_hi, Q_lo, K_hi, K_lo);
    // V^T = wv^T @ x^T, plain fp16, tile 128x64
    dim3 gvt(SEQ / 64, DMODEL / 128);  // (64,8)
    gemm_h16_n64<1><<<gvt, 256, 0, stream>>>(wvT, DMODEL, x_hi, DMODEL,
                                             nullptr, VT, SEQ, DMODEL);

    // 3) scores + tile-softmax (16x16x32): P = exp(QK^T/32 - m_t)
    dim3 gs(SEQ / 128, SEQ / 128);     // (32,32)
    gemm_score<<<gs, 256, 0, stream>>>(Q_hi, Q_lo, K_hi, K_lo,
                                       P, Marr, Larr, 1.0f / 32.0f);

    // 4) finalize: P *= c_t(row)  (in place, exact softmax)
    reduce_scale<<<SEQ, 256, 0, stream>>>(Marr, Larr, P);

    // 5) out = P @ V, plain fp16
    dim3 go(DMODEL / 64, SEQ / 128);   // (16,32)
    gemm_h16_n64<0><<<go, 256, 0, stream>>>(P, SEQ, VT, SEQ,
                                            out, nullptr, DMODEL, SEQ);
}